// Round 17
// baseline (297.795 us; speedup 1.0000x reference)
//
#include <hip/hip_runtime.h>
#include <stdint.h>

typedef __attribute__((ext_vector_type(4)))  float    f32x4;
typedef __attribute__((ext_vector_type(16))) float    f32x16;
typedef __attribute__((ext_vector_type(8)))  _Float16 f16x8;
typedef __attribute__((ext_vector_type(8)))  __bf16   bf16x8;

#define SEQ   2048
#define DH    64
#define BQ    128            // q rows per block (4 q-waves x 32)
#define BK    64             // keys per tile
#define NT    (SEQ / BK)     // 32 k-tiles per batch
#define HNT   (NT / 2)       // 16 tiles per key-half (split-K factor 2)
#define ROWE  72             // padded row: 144 B stride (16B-aligned, proven 0-conflict)
#define TILEE (64 * ROWE)    // 4608 elems = 9216 B per tile
#define L2E   1.44269504088896340736f

#if __has_builtin(__builtin_amdgcn_exp2f)
static __device__ __forceinline__ float fast_exp2(float x) { return __builtin_amdgcn_exp2f(x); }
#else
static __device__ __forceinline__ float fast_exp2(float x) {
  float r; asm("v_exp_f32 %0, %1" : "=v"(r) : "v"(x)); return r;
}
#endif
static __device__ __forceinline__ uint32_t pack2_bf16(float a, float b) {
  union { __bf16 h[2]; uint32_t u; } cv;
  cv.h[0] = (__bf16)a; cv.h[1] = (__bf16)b;
  return cv.u;
}
union frag_u { uint32_t u[4]; bf16x8 v; };

typedef const __attribute__((address_space(1))) uint32_t* gp1_t;
typedef __attribute__((address_space(3))) uint32_t*       lp3_t;

// sigma relabel (HW-verified): C-layout row m of S^T=K*Q^T carries key sigma(m).
__host__ __device__ inline int sigma32(int m) {
  int b = m & 3, h = (m >> 2) & 1, c = m >> 3;
  return ((c & 1) << 4) | (h << 3) | ((c >> 1) << 2) | b;
}

// ---- tile converters (exact prepass math, 256-thread cooperative, t = tid&255)
static __device__ __forceinline__ void convK_tile(const float* __restrict__ src,
                                                  _Float16* __restrict__ dst, int t) {
  const int row = t >> 2, c = (t & 3) << 4;
  const int srow = (row & 32) | sigma32(row & 31);   // row holds key sigma(row)
  const float* sp = src + srow * DH + c;
  f32x4 x0 = *(const f32x4*)(sp + 0),  x1 = *(const f32x4*)(sp + 4);
  f32x4 x2 = *(const f32x4*)(sp + 8),  x3 = *(const f32x4*)(sp + 12);
  f16x8 h0, h1;
#pragma unroll
  for (int j = 0; j < 4; ++j) {
    h0[j] = (_Float16)x0[j]; h0[j + 4] = (_Float16)x1[j];
    h1[j] = (_Float16)x2[j]; h1[j + 4] = (_Float16)x3[j];
  }
  *(f16x8*)(dst + row * ROWE + c)     = h0;
  *(f16x8*)(dst + row * ROWE + c + 8) = h1;
}
static __device__ __forceinline__ void convV_tile(const float* __restrict__ src,
                                                  __bf16* __restrict__ dst, int t) {
#pragma unroll
  for (int it = 0; it < 4; ++it) {
    int task = t + it * 256;
    int d = task & 63, g = task >> 6;        // 16 key-groups x 64 d
    const float* sp = src + (size_t)(4 * g) * DH + d;   // coalesced across d
    __bf16 hv[4];
#pragma unroll
    for (int j = 0; j < 4; ++j) hv[j] = (__bf16)sp[(size_t)j * DH];
    *(uint64_t*)(dst + d * ROWE + 4 * g) = *(uint64_t*)hv;
  }
}

// ---------------- fused v17: in-kernel K/V conversion (flags + bounded-spin
// self-convert fallback -> deadlock-free) + v16's main loop verbatim.
// Grid 512 = 2 blocks/CU capacity; 16 consumer blocks of a batch share an XCD.
__global__ __launch_bounds__(512, 2)
void flash_attn_v17(const float* __restrict__ Q, const float* __restrict__ K,
                    const float* __restrict__ V, _Float16* __restrict__ Kh,
                    __bf16* __restrict__ Vh, unsigned* __restrict__ flags,
                    float* __restrict__ O) {
  __shared__ _Float16 Ksb[2][2][64][ROWE];   // [key-half][dbuf] 36864 B
  __shared__ __bf16   Vtb[2][2][64][ROWE];   // 36864 B
  __shared__ float    Ls[4][32];             // per-qwave 1/rowsum broadcast
  __shared__ unsigned missMask;

  const int tid  = threadIdx.x;
  const int wv   = tid >> 6;             // 0..7
  const int qw   = wv & 3;               // q-wave: which 32 q-rows
  const int kh   = wv >> 2;              // key-half: 0 -> tiles 0..15, 1 -> 16..31
  const int lane = tid & 63;
  const int hfw  = lane >> 5;
  const int l31  = lane & 31;

  const int batch = blockIdx.x & 31;     // batch-major: 16 q-blocks share an XCD
  const int qblk  = blockIdx.x >> 5;

  const float* Qb  = Q + (size_t)batch * SEQ * DH;
  const float* Kr  = K + (size_t)batch * SEQ * DH;   // raw fp32 K
  const float* Vr  = V + (size_t)batch * SEQ * DH;   // raw fp32 V
  float*       Ob  = O + (size_t)batch * SEQ * DH;
  _Float16*    KhB = Kh + (size_t)batch * NT * TILEE;
  __bf16*      VhB = Vh + (size_t)batch * NT * TILEE;
  unsigned*    fb  = flags + batch * NT;

  // ---- fused conversion: this block converts tiles 2*qblk, 2*qblk+1 (K and V)
  {
    const int myt = 2 * qblk + (tid >> 8);   // tid>>8 in {0,1}
    const int t8  = tid & 255;
    convK_tile(Kr + (size_t)myt * 64 * DH, KhB + (size_t)myt * TILEE, t8);
    convV_tile(Vr + (size_t)myt * 64 * DH, VhB + (size_t)myt * TILEE, t8);
  }
  __threadfence();                       // each thread's stores device-visible
  __syncthreads();
  if (tid < 2) atomicExch(&fb[2 * qblk + tid], 1u);

  // Q fragments (B-operand of S^T): lane holds Q[q=l31][d=ks*16+hfw*8+j], *log2e
  const int qrow = qblk * BQ + qw * 32 + l31;
  f16x8 qf[4];
  {
    const float* qp = Qb + (size_t)qrow * DH + hfw * 8;
#pragma unroll
    for (int ks = 0; ks < 4; ++ks) {
      f32x4 a = *(const f32x4*)(qp + ks * 16);
      f32x4 b = *(const f32x4*)(qp + ks * 16 + 4);
#pragma unroll
      for (int j = 0; j < 4; ++j) {
        qf[ks][j]     = (_Float16)(a[j] * L2E);
        qf[ks][j + 4] = (_Float16)(b[j] * L2E);
      }
    }
  }

  // ---- readiness: all 32 tiles of this batch. Bounded spin (threads 0..31,
  // one flag each) + whole-block self-convert fallback (identical writes are
  // benign) -> no deadlock even if co-residency assumptions fail.
  if (tid == 0) missMask = 0u;
  __syncthreads();
  if (tid < NT) {
    bool ok = false;
    for (int sp = 0; sp < 1000 && !ok; ++sp)
      ok = (atomicAdd(&fb[tid], 0u) != 0u);
    if (!ok) atomicOr(&missMask, 1u << tid);
  }
  __syncthreads();
  {
    unsigned mm = missMask;
    if (mm) {
      while (mm) {
        int t = __ffs(mm) - 1; mm &= mm - 1;
        convK_tile(Kr + (size_t)t * 64 * DH, KhB + (size_t)t * TILEE, tid & 255);
        convV_tile(Vr + (size_t)t * 64 * DH, VhB + (size_t)t * TILEE, tid & 255);
      }
      __threadfence();
    }
  }
  __syncthreads();

  // ================= main loop: verbatim v16 =================
  const uint32_t* Kt0 = (const uint32_t*)KhB;
  const uint32_t* Vt0 = (const uint32_t*)VhB;

  auto stage = [&](int t, int buf) {
    const uint32_t* kgp = Kt0 + (size_t)t * (TILEE / 2);
    const uint32_t* vgp = Vt0 + (size_t)t * (TILEE / 2);
    lp3_t kl = (lp3_t)&Ksb[kh][buf][0][0];
    lp3_t vl = (lp3_t)&Vtb[kh][buf][0][0];
#pragma unroll
    for (int j = qw; j < 9; j += 4) {
      __builtin_amdgcn_global_load_lds((gp1_t)(kgp + j * 256 + lane * 4), kl + j * 256, 16, 0, 0);
      __builtin_amdgcn_global_load_lds((gp1_t)(vgp + j * 256 + lane * 4), vl + j * 256, 16, 0, 0);
    }
  };

  f32x16 acc0 = {}, acc1 = {};   // O partial: col = d = l31 / l31+32, rows = q
  float lsum = 0.f;              // partial row-sum for q = l31 over this half's keys

  const int t0 = kh * HNT;
  stage(t0, 0);

#pragma unroll 1
  for (int li = 0; li < HNT; ++li) {
    __syncthreads();   // vmcnt(0) drain: tile t0+li resident; prior buf reads done
    if (li + 1 < HNT) stage(t0 + li + 1, (li + 1) & 1);
    const int buf = li & 1;

    // ---- S^T = K·Q^T (sigma-relabeled K rows): C col = q = l31, rows = keys
    __builtin_amdgcn_s_setprio(1);
    f32x16 s0 = {}, s1 = {};
#pragma unroll
    for (int ks = 0; ks < 4; ++ks) {
      int dof = ks * 16 + hfw * 8;
      f16x8 kf0 = *(const f16x8*)&Ksb[kh][buf][l31][dof];
      f16x8 kf1 = *(const f16x8*)&Ksb[kh][buf][l31 + 32][dof];
      s0 = __builtin_amdgcn_mfma_f32_32x32x16_f16(kf0, qf[ks], s0, 0, 0, 0);  // keys 0..31
      s1 = __builtin_amdgcn_mfma_f32_32x32x16_f16(kf1, qf[ks], s1, 0, 0, 0);  // keys 32..63
    }
    __builtin_amdgcn_s_setprio(0);

    // ---- P = exp2(S); repack into natural-key-order A-fragments (registers)
    frag_u fr[4];
#pragma unroll
    for (int t2 = 0; t2 < 2; ++t2) {
      const f32x16& s = t2 ? s1 : s0;
      float p[16];
#pragma unroll
      for (int j = 0; j < 16; ++j) p[j] = fast_exp2(s[j]);
      float a0 = (p[0] + p[1]) + (p[2] + p[3]);
      float a1 = (p[4] + p[5]) + (p[6] + p[7]);
      float a2 = (p[8] + p[9]) + (p[10] + p[11]);
      float a3 = (p[12] + p[13]) + (p[14] + p[15]);
      lsum += (a0 + a1) + (a2 + a3);
      fr[2 * t2    ].u[0] = pack2_bf16(p[0],  p[1]);
      fr[2 * t2    ].u[1] = pack2_bf16(p[2],  p[3]);
      fr[2 * t2    ].u[2] = pack2_bf16(p[8],  p[9]);
      fr[2 * t2    ].u[3] = pack2_bf16(p[10], p[11]);
      fr[2 * t2 + 1].u[0] = pack2_bf16(p[4],  p[5]);
      fr[2 * t2 + 1].u[1] = pack2_bf16(p[6],  p[7]);
      fr[2 * t2 + 1].u[2] = pack2_bf16(p[12], p[13]);
      fr[2 * t2 + 1].u[3] = pack2_bf16(p[14], p[15]);
    }

    // ---- O += P·V : A = P frags (registers), B = V^T (LDS, JIT reads)
    __builtin_amdgcn_s_setprio(1);
#pragma unroll
    for (int ks = 0; ks < 4; ++ks) {
      int kof = ks * 16 + hfw * 8;
      bf16x8 v0 = *(const bf16x8*)&Vtb[kh][buf][l31][kof];
      bf16x8 v1 = *(const bf16x8*)&Vtb[kh][buf][l31 + 32][kof];
      acc0 = __builtin_amdgcn_mfma_f32_32x32x16_bf16(fr[ks].v, v0, acc0, 0, 0, 0);
      acc1 = __builtin_amdgcn_mfma_f32_32x32x16_bf16(fr[ks].v, v1, acc1, 0, 0, 0);
    }
    __builtin_amdgcn_s_setprio(0);
  }

  // ---- split-K combine: exp2-partials are exactly additive. Reuse the dead
  // K/V LDS as the combine buffer (33-stride: lane-major -> conflict-free).
  float tot = lsum + __shfl_xor(lsum, 32);   // this half's full rowsum for q=l31
  __syncthreads();                           // all waves done with tile LDS
  float* cb = (float*)&Ksb[0][0][0][0];      // 4*64*33*4B = 33.8 KB <= 36.8 KB
  float* sb = (float*)&Vtb[0][0][0][0];      // 4*64*4B
  if (kh == 1) {
    const int base = (qw * 64 + lane) * 33;
#pragma unroll
    for (int j = 0; j < 16; ++j) {
      cb[base + j]      = acc0[j];
      cb[base + j + 16] = acc1[j];
    }
    sb[qw * 64 + lane] = tot;
  }
  __syncthreads();
  if (kh == 0) {
    const int base = (qw * 64 + lane) * 33;
    float tot2 = tot + sb[qw * 64 + lane];   // partner half, same q-rows
    Ls[qw][l31] = __builtin_amdgcn_rcpf(tot2);
#pragma unroll
    for (int j = 0; j < 16; ++j) {
      acc0[j] += cb[base + j];
      acc1[j] += cb[base + j + 16];
    }
#pragma unroll
    for (int j = 0; j < 16; ++j) {
      int row = (j & 3) + 8 * (j >> 2) + 4 * hfw;
      float inv = Ls[qw][row];
      size_t off = (size_t)(qblk * BQ + qw * 32 + row) * DH + l31;
      Ob[off]      = acc0[j] * inv;
      Ob[off + 32] = acc1[j] * inv;
    }
  }
}

extern "C" void kernel_launch(void* const* d_in, const int* in_sizes, int n_in,
                              void* d_out, int out_size, void* d_ws, size_t ws_size,
                              hipStream_t stream) {
  (void)in_sizes; (void)n_in; (void)ws_size; (void)out_size;
  const float* q = (const float*)d_in[0];
  const float* k = (const float*)d_in[1];
  const float* v = (const float*)d_in[2];
  float* o = (float*)d_out;
  // ws: Kh 9.44 MB | Vh 9.44 MB | flags 4 KB  (~18.9 MB total)
  const size_t kvbytes = (size_t)32 * NT * TILEE * sizeof(_Float16);
  _Float16* Kh    = (_Float16*)d_ws;
  __bf16*   Vh    = (__bf16*)((char*)d_ws + kvbytes);
  unsigned* flags = (unsigned*)((char*)d_ws + 2 * kvbytes);

  hipMemsetAsync(flags, 0, (size_t)32 * NT * sizeof(unsigned), stream);
  flash_attn_v17<<<dim3(32 * (SEQ / BQ)), dim3(512), 0, stream>>>(q, k, v, Kh, Vh, flags, o);
}

// Round 18
// 137.077 us; speedup vs baseline: 2.1725x; 2.1725x over previous
//
#include <hip/hip_runtime.h>
#include <stdint.h>

typedef __attribute__((ext_vector_type(4)))  float    f32x4;
typedef __attribute__((ext_vector_type(16))) float    f32x16;
typedef __attribute__((ext_vector_type(8)))  _Float16 f16x8;
typedef __attribute__((ext_vector_type(8)))  __bf16   bf16x8;

#define SEQ   2048
#define DH    64
#define BQ    128            // q rows per block (4 q-waves x 32)
#define BK    64             // keys per tile
#define NT    (SEQ / BK)     // 32 k-tiles per batch
#define HNT   (NT / 2)       // 16 tiles per key-half (split-K factor 2)
#define ROWE  72             // padded row: 144 B stride (16B-aligned, proven 0-conflict)
#define L2E   1.44269504088896340736f

#if __has_builtin(__builtin_amdgcn_exp2f)
static __device__ __forceinline__ float fast_exp2(float x) { return __builtin_amdgcn_exp2f(x); }
#else
static __device__ __forceinline__ float fast_exp2(float x) {
  float r; asm("v_exp_f32 %0, %1" : "=v"(r) : "v"(x)); return r;
}
#endif
static __device__ __forceinline__ uint32_t pack2_bf16(float a, float b) {
  union { __bf16 h[2]; uint32_t u; } cv;
  cv.h[0] = (__bf16)a; cv.h[1] = (__bf16)b;
  return cv.u;
}
union frag_u { uint32_t u[4]; bf16x8 v; };

// sigma relabel (HW-verified): C-layout row m of S^T=K*Q^T carries key sigma(m).
__host__ __device__ inline int sigma32(int m) {
  int b = m & 3, h = (m >> 2) & 1, c = m >> 3;
  return ((c & 1) << 4) | (h << 3) | ((c >> 1) << 2) | b;
}

// ---------------- fused v18: NO prepass, NO workspace, NO flags/atomics
// (v17's flag-spin cost 200us in L2 atomic serialization). Each block
// converts its own fp32 K/V tiles straight into LDS (exact prepass math).
// Reads are L2-hits: 16 consumer blocks of a batch share one XCD, batch
// K+V fp32 = 1MB. T14 split: loads for tile i+1 issue BEFORE compute(i),
// cvt+LDS-write after -> full tile of latency cover. v16 main loop verbatim.
__global__ __launch_bounds__(512, 2)
void flash_attn_v18(const float* __restrict__ Q, const float* __restrict__ K,
                    const float* __restrict__ V, float* __restrict__ O) {
  __shared__ _Float16 Ksb[2][2][64][ROWE];   // [key-half][dbuf] 36864 B
  __shared__ __bf16   Vtb[2][2][64][ROWE];   // 36864 B
  __shared__ float    Ls[4][32];             // per-qwave 1/rowsum broadcast

  const int tid  = threadIdx.x;
  const int wv   = tid >> 6;             // 0..7
  const int qw   = wv & 3;               // q-wave: which 32 q-rows
  const int kh   = wv >> 2;              // key-half: 0 -> tiles 0..15, 1 -> 16..31
  const int lane = tid & 63;
  const int hfw  = lane >> 5;
  const int l31  = lane & 31;

  const int batch = blockIdx.x & 31;     // batch-major: 16 q-blocks share an XCD
  const int qblk  = blockIdx.x >> 5;

  const float* Qb = Q + (size_t)batch * SEQ * DH;
  const float* Kr = K + (size_t)batch * SEQ * DH;   // raw fp32 K (L2-resident)
  const float* Vr = V + (size_t)batch * SEQ * DH;   // raw fp32 V (L2-resident)
  float*       Ob = O + (size_t)batch * SEQ * DH;

  // ---- per-thread conversion geometry (constant across tiles; prepass math)
  const int t8    = qw * 64 + lane;          // 0..255 within this key-half
  const int krow  = t8 >> 2;                 // K: LDS row this thread fills
  const int kc    = (t8 & 3) << 4;           // K: d-offset (16 elems)
  const int ksrow = (krow & 32) | sigma32(krow & 31);   // sigma'd source row
  const float* kbase = Kr + (size_t)ksrow * DH + kc;

  // K loads: 4x f32x4 from one sigma'd row (64B, L2-hit).
  // V loads: 16 scalar f32, d=lane coalesced across the wave (256B/instr).
  auto convLoad = [&](int t, f32x4* kx, float (*vx)[4]) {
    const float* kp = kbase + (size_t)t * 64 * DH;
#pragma unroll
    for (int u = 0; u < 4; ++u) kx[u] = *(const f32x4*)(kp + 4 * u);
    const float* vp0 = Vr + (size_t)t * 64 * DH + lane;
#pragma unroll
    for (int it = 0; it < 4; ++it) {
      const float* vp = vp0 + (size_t)(4 * (qw + 4 * it)) * DH;
#pragma unroll
      for (int j = 0; j < 4; ++j) vx[it][j] = vp[(size_t)j * DH];
    }
  };
  // cvt + LDS write (identical output bytes to the old prepass tiles)
  auto convWrite = [&](int buf, const f32x4* kx, const float (*vx)[4]) {
    f16x8 h0, h1;
#pragma unroll
    for (int j = 0; j < 4; ++j) {
      h0[j] = (_Float16)kx[0][j]; h0[j + 4] = (_Float16)kx[1][j];
      h1[j] = (_Float16)kx[2][j]; h1[j + 4] = (_Float16)kx[3][j];
    }
    *(f16x8*)&Ksb[kh][buf][krow][kc]     = h0;
    *(f16x8*)&Ksb[kh][buf][krow][kc + 8] = h1;
#pragma unroll
    for (int it = 0; it < 4; ++it) {
      __bf16 hv[4];
#pragma unroll
      for (int j = 0; j < 4; ++j) hv[j] = (__bf16)vx[it][j];
      *(uint64_t*)&Vtb[kh][buf][lane][4 * (qw + 4 * it)] = *(uint64_t*)hv;
    }
  };

  // Q fragments (B-operand of S^T): lane holds Q[q=l31][d=ks*16+hfw*8+j], *log2e
  const int qrow = qblk * BQ + qw * 32 + l31;
  f16x8 qf[4];
  {
    const float* qp = Qb + (size_t)qrow * DH + hfw * 8;
#pragma unroll
    for (int ks = 0; ks < 4; ++ks) {
      f32x4 a = *(const f32x4*)(qp + ks * 16);
      f32x4 b = *(const f32x4*)(qp + ks * 16 + 4);
#pragma unroll
      for (int j = 0; j < 4; ++j) {
        qf[ks][j]     = (_Float16)(a[j] * L2E);
        qf[ks][j + 4] = (_Float16)(b[j] * L2E);
      }
    }
  }

  f32x16 acc0 = {}, acc1 = {};   // O partial: col = d = l31 / l31+32, rows = q
  float lsum = 0.f;              // partial row-sum for q = l31 over this half's keys

  const int t0 = kh * HNT;

  // prologue: convert tile t0 into buf0
  f32x4 kx[4]; float vx[4][4];
  convLoad(t0, kx, vx);
  convWrite(0, kx, vx);

#pragma unroll 1
  for (int li = 0; li < HNT; ++li) {
    __syncthreads();   // buf(li&1) fully written by all converters of this half
    const int buf = li & 1;
    if (li + 1 < HNT) convLoad(t0 + li + 1, kx, vx);   // issue early (T14)

    // ---- S^T = K·Q^T (sigma-relabeled K rows): C col = q = l31, rows = keys
    __builtin_amdgcn_s_setprio(1);
    f32x16 s0 = {}, s1 = {};
#pragma unroll
    for (int ks = 0; ks < 4; ++ks) {
      int dof = ks * 16 + hfw * 8;
      f16x8 kf0 = *(const f16x8*)&Ksb[kh][buf][l31][dof];
      f16x8 kf1 = *(const f16x8*)&Ksb[kh][buf][l31 + 32][dof];
      s0 = __builtin_amdgcn_mfma_f32_32x32x16_f16(kf0, qf[ks], s0, 0, 0, 0);  // keys 0..31
      s1 = __builtin_amdgcn_mfma_f32_32x32x16_f16(kf1, qf[ks], s1, 0, 0, 0);  // keys 32..63
    }
    __builtin_amdgcn_s_setprio(0);

    // ---- P = exp2(S); repack into natural-key-order A-fragments (registers)
    frag_u fr[4];
#pragma unroll
    for (int t2 = 0; t2 < 2; ++t2) {
      const f32x16& s = t2 ? s1 : s0;
      float p[16];
#pragma unroll
      for (int j = 0; j < 16; ++j) p[j] = fast_exp2(s[j]);
      float a0 = (p[0] + p[1]) + (p[2] + p[3]);
      float a1 = (p[4] + p[5]) + (p[6] + p[7]);
      float a2 = (p[8] + p[9]) + (p[10] + p[11]);
      float a3 = (p[12] + p[13]) + (p[14] + p[15]);
      lsum += (a0 + a1) + (a2 + a3);
      fr[2 * t2    ].u[0] = pack2_bf16(p[0],  p[1]);
      fr[2 * t2    ].u[1] = pack2_bf16(p[2],  p[3]);
      fr[2 * t2    ].u[2] = pack2_bf16(p[8],  p[9]);
      fr[2 * t2    ].u[3] = pack2_bf16(p[10], p[11]);
      fr[2 * t2 + 1].u[0] = pack2_bf16(p[4],  p[5]);
      fr[2 * t2 + 1].u[1] = pack2_bf16(p[6],  p[7]);
      fr[2 * t2 + 1].u[2] = pack2_bf16(p[12], p[13]);
      fr[2 * t2 + 1].u[3] = pack2_bf16(p[14], p[15]);
    }

    // ---- O += P·V : A = P frags (registers), B = V^T (LDS, JIT reads)
    __builtin_amdgcn_s_setprio(1);
#pragma unroll
    for (int ks = 0; ks < 4; ++ks) {
      int kof = ks * 16 + hfw * 8;
      bf16x8 v0 = *(const bf16x8*)&Vtb[kh][buf][l31][kof];
      bf16x8 v1 = *(const bf16x8*)&Vtb[kh][buf][l31 + 32][kof];
      acc0 = __builtin_amdgcn_mfma_f32_32x32x16_bf16(fr[ks].v, v0, acc0, 0, 0, 0);
      acc1 = __builtin_amdgcn_mfma_f32_32x32x16_bf16(fr[ks].v, v1, acc1, 0, 0, 0);
    }
    __builtin_amdgcn_s_setprio(0);

    if (li + 1 < HNT) convWrite(buf ^ 1, kx, vx);   // write late (T14)
  }

  // ---- split-K combine: exp2-partials are exactly additive. Reuse the dead
  // K/V LDS as the combine buffer (33-stride: lane-major -> conflict-free).
  float tot = lsum + __shfl_xor(lsum, 32);   // this half's full rowsum for q=l31
  __syncthreads();                           // all waves done with tile LDS
  float* cb = (float*)&Ksb[0][0][0][0];      // 4*64*33*4B = 33.8 KB <= 36.8 KB
  float* sb = (float*)&Vtb[0][0][0][0];      // 4*64*4B
  if (kh == 1) {
    const int base = (qw * 64 + lane) * 33;
#pragma unroll
    for (int j = 0; j < 16; ++j) {
      cb[base + j]      = acc0[j];
      cb[base + j + 16] = acc1[j];
    }
    sb[qw * 64 + lane] = tot;
  }
  __syncthreads();
  if (kh == 0) {
    const int base = (qw * 64 + lane) * 33;
    float tot2 = tot + sb[qw * 64 + lane];   // partner half, same q-rows
    Ls[qw][l31] = __builtin_amdgcn_rcpf(tot2);
#pragma unroll
    for (int j = 0; j < 16; ++j) {
      acc0[j] += cb[base + j];
      acc1[j] += cb[base + j + 16];
    }
#pragma unroll
    for (int j = 0; j < 16; ++j) {
      int row = (j & 3) + 8 * (j >> 2) + 4 * hfw;
      float inv = Ls[qw][row];
      size_t off = (size_t)(qblk * BQ + qw * 32 + row) * DH + l31;
      Ob[off]      = acc0[j] * inv;
      Ob[off + 32] = acc1[j] * inv;
    }
  }
}

extern "C" void kernel_launch(void* const* d_in, const int* in_sizes, int n_in,
                              void* d_out, int out_size, void* d_ws, size_t ws_size,
                              hipStream_t stream) {
  (void)in_sizes; (void)n_in; (void)d_ws; (void)ws_size; (void)out_size;
  const float* q = (const float*)d_in[0];
  const float* k = (const float*)d_in[1];
  const float* v = (const float*)d_in[2];
  float* o = (float*)d_out;
  // single fused launch: no prepass, no workspace, no flags
  flash_attn_v18<<<dim3(32 * (SEQ / BQ)), dim3(512), 0, stream>>>(q, k, v, o);
}